// Round 1
// baseline (62.874 us; speedup 1.0000x reference)
//
#include <hip/hip_runtime.h>
#include <cfloat>
#include <climits>

#define B_   8
#define N1_  1024
#define N2_  4096
#define C_   256

// ---------------------------------------------------------------------------
// Kernel 1: 3-NN search. One block = (b, tile of 64 queries). 4 threads/query.
// Replicates the reference's fp32 arithmetic exactly:
//   d2 = (|p2|^2 - 2*dot(p2,p1)) + |p1|^2, all left-to-right, no FMA.
// ---------------------------------------------------------------------------

__device__ __forceinline__ bool better_(float d, int i, float D, int I) {
    // strict-less with lower-index tie-break (matches top_k tie order)
    return (d < D) || (d == D && i < I);
}

__device__ __forceinline__ void ins_(float d, int i,
                                     float& d0, float& d1, float& d2,
                                     int& i0, int& i1, int& i2) {
    if (better_(d, i, d2, i2)) {
        d2 = d; i2 = i;
        if (better_(d2, i2, d1, i1)) {
            float td = d1; d1 = d2; d2 = td;
            int   ti = i1; i1 = i2; i2 = ti;
            if (better_(d1, i1, d0, i0)) {
                td = d0; d0 = d1; d1 = td;
                ti = i0; i0 = i1; i1 = ti;
            }
        }
    }
}

__global__ __launch_bounds__(256) void knn_kernel(
    const float* __restrict__ p1, const float* __restrict__ p2,
    int4* __restrict__ wsi, float4* __restrict__ wsw) {
    __shared__ float4 pts[N1_];   // (x, y, z, |p1|^2) per coarse point: 16 KB

    const int tid   = threadIdx.x;
    const int b     = blockIdx.x >> 6;   // 64 query-tiles per batch
    const int mtile = blockIdx.x & 63;

    // Stage p1[b] with precomputed squared norm (ref order: (x^2+y^2)+z^2).
    for (int j = tid; j < N1_; j += 256) {
        float x = p1[((size_t)b * N1_ + j) * 3 + 0];
        float y = p1[((size_t)b * N1_ + j) * 3 + 1];
        float z = p1[((size_t)b * N1_ + j) * 3 + 2];
        float s1 = __fadd_rn(__fadd_rn(__fmul_rn(x, x), __fmul_rn(y, y)),
                             __fmul_rn(z, z));
        pts[j] = make_float4(x, y, z, s1);
    }
    __syncthreads();

    const int q = tid >> 2;       // query within tile, 0..63
    const int t = tid & 3;        // sub-thread within query
    const int m = mtile * 64 + q;

    const size_t pbase = ((size_t)b * N2_ + m) * 3;
    const float x2 = p2[pbase + 0];
    const float y2 = p2[pbase + 1];
    const float z2 = p2[pbase + 2];
    const float s2 = __fadd_rn(__fadd_rn(__fmul_rn(x2, x2), __fmul_rn(y2, y2)),
                               __fmul_rn(z2, z2));

    float d0 = FLT_MAX, d1 = FLT_MAX, d2 = FLT_MAX;
    int   i0 = INT_MAX, i1 = INT_MAX, i2 = INT_MAX;

    for (int n = t; n < N1_; n += 4) {
        float4 p = pts[n];
        float dot = __fadd_rn(__fadd_rn(__fmul_rn(x2, p.x), __fmul_rn(y2, p.y)),
                              __fmul_rn(z2, p.z));
        float dd = __fadd_rn(__fsub_rn(s2, __fmul_rn(2.0f, dot)), p.w);
        ins_(dd, n, d0, d1, d2, i0, i1, i2);
    }

    // Butterfly-merge the 4 partial top-3 lists of this query.
    for (int mask = 1; mask < 4; mask <<= 1) {
        float pd0 = __shfl_xor(d0, mask, 4);
        float pd1 = __shfl_xor(d1, mask, 4);
        float pd2 = __shfl_xor(d2, mask, 4);
        int   pi0 = __shfl_xor(i0, mask, 4);
        int   pi1 = __shfl_xor(i1, mask, 4);
        int   pi2 = __shfl_xor(i2, mask, 4);
        ins_(pd0, pi0, d0, d1, d2, i0, i1, i2);
        ins_(pd1, pi1, d0, d1, d2, i0, i1, i2);
        ins_(pd2, pi2, d0, d1, d2, i0, i1, i2);
    }

    if (t == 0) {
        // weights: recip = 1/(d + 1e-8), normalized (sum order (r0+r1)+r2)
        float r0 = 1.0f / __fadd_rn(d0, 1e-8f);
        float r1 = 1.0f / __fadd_rn(d1, 1e-8f);
        float r2 = 1.0f / __fadd_rn(d2, 1e-8f);
        float s  = __fadd_rn(__fadd_rn(r0, r1), r2);
        wsi[(size_t)b * N2_ + m] = make_int4(i0, i1, i2, 0);
        wsw[(size_t)b * N2_ + m] = make_float4(r0 / s, r1 / s, r2 / s, 0.0f);
    }
}

// ---------------------------------------------------------------------------
// Kernel 2: gather + blend. One block = (b, 8-channel slice, half of N2).
// x1 slice staged in LDS (32 KB); idx/w read coalesced; output writes
// coalesced (lane = consecutive m).
// ---------------------------------------------------------------------------

__global__ __launch_bounds__(256) void blend_kernel(
    const float* __restrict__ x1, const int4* __restrict__ wsi,
    const float4* __restrict__ wsw, float* __restrict__ out) {
    __shared__ float L[8][N1_];   // 32 KB

    int bid = blockIdx.x;
    const int mhalf = bid & 1; bid >>= 1;
    const int ct    = bid & 31;          // channel tile (8 channels each)
    const int b     = bid >> 5;
    const int tid   = threadIdx.x;

    const float* src = x1 + ((size_t)b * C_ + ct * 8) * N1_;
    float4* Lv = reinterpret_cast<float4*>(&L[0][0]);
    const float4* Sv = reinterpret_cast<const float4*>(src);
    for (int j = tid; j < 8 * N1_ / 4; j += 256) Lv[j] = Sv[j];
    __syncthreads();

    for (int mb = 0; mb < 8; ++mb) {
        const int m = mhalf * 2048 + mb * 256 + tid;
        const int4   id = wsi[(size_t)b * N2_ + m];
        const float4 w  = wsw[(size_t)b * N2_ + m];
#pragma unroll
        for (int r = 0; r < 8; ++r) {
            float a  = L[r][id.x];
            float bb = L[r][id.y];
            float cc = L[r][id.z];
            // ref: sum_k gathered*weight, k ascending, no FMA
            float acc = __fadd_rn(__fadd_rn(__fmul_rn(a,  w.x),
                                            __fmul_rn(bb, w.y)),
                                  __fmul_rn(cc, w.z));
            out[((size_t)b * C_ + (size_t)ct * 8 + r) * N2_ + m] = acc;
        }
    }
}

extern "C" void kernel_launch(void* const* d_in, const int* in_sizes, int n_in,
                              void* d_out, int out_size, void* d_ws, size_t ws_size,
                              hipStream_t stream) {
    const float* p1 = (const float*)d_in[0];   // [B, N1, 3]
    const float* x1 = (const float*)d_in[1];   // [B, C, N1]
    const float* p2 = (const float*)d_in[2];   // [B, N2, 3]
    float* out = (float*)d_out;                // [B, C, N2]

    int4*   wsi = (int4*)d_ws;                                   // 512 KB
    float4* wsw = (float4*)((char*)d_ws + (size_t)B_ * N2_ * sizeof(int4));

    knn_kernel<<<B_ * (N2_ / 64), 256, 0, stream>>>(p1, p2, wsi, wsw);
    blend_kernel<<<B_ * (C_ / 8) * 2, 256, 0, stream>>>(x1, wsi, wsw, out);
}

// Round 2
// 33.085 us; speedup vs baseline: 1.9004x; 1.9004x over previous
//
#include <hip/hip_runtime.h>
#include <cfloat>
#include <climits>

#define B_   8
#define N1_  1024
#define N2_  4096
#define C_   256
#define TPQ  16                 // threads per query
#define QPB  (256 / TPQ)        // 16 queries per block

// ---------------------------------------------------------------------------
// Kernel 1: 3-NN search. 16 threads/query, 16 queries/block, 2048 blocks.
// Branchless sorted top-3 via v_min_f32 / v_med3_f32 + cndmask index chain.
// Reference arithmetic replicated exactly: d2 = (|p2|^2 - 2*dot) + |p1|^2,
// left-to-right, no FMA (2*dot realized via pre-doubled coords — exact).
// ---------------------------------------------------------------------------

__device__ __forceinline__ bool better_(float d, int i, float D, int I) {
    return (d < D) || (d == D && i < I);   // lexicographic (d, index)
}

__device__ __forceinline__ void ins_(float d, int i,
                                     float& d0, float& d1, float& d2,
                                     int& i0, int& i1, int& i2) {
    if (better_(d, i, d2, i2)) {
        d2 = d; i2 = i;
        if (better_(d2, i2, d1, i1)) {
            float td = d1; d1 = d2; d2 = td;
            int   ti = i1; i1 = i2; i2 = ti;
            if (better_(d1, i1, d0, i0)) {
                td = d0; d0 = d1; d1 = td;
                ti = i0; i0 = i1; i1 = ti;
            }
        }
    }
}

__global__ __launch_bounds__(256) void knn_kernel(
    const float* __restrict__ p1, const float* __restrict__ p2,
    int4* __restrict__ wsi, float4* __restrict__ wsw) {
    __shared__ float4 pts[N1_];   // (2x, 2y, 2z, |p1|^2): 16 KB

    const int tid   = threadIdx.x;
    const int b     = blockIdx.x >> 8;     // N2/QPB = 256 tiles per batch
    const int mtile = blockIdx.x & 255;

    for (int j = tid; j < N1_; j += 256) {
        float x = p1[((size_t)b * N1_ + j) * 3 + 0];
        float y = p1[((size_t)b * N1_ + j) * 3 + 1];
        float z = p1[((size_t)b * N1_ + j) * 3 + 2];
        float s1 = __fadd_rn(__fadd_rn(__fmul_rn(x, x), __fmul_rn(y, y)),
                             __fmul_rn(z, z));
        pts[j] = make_float4(x + x, y + y, z + z, s1);  // 2x exact
    }
    __syncthreads();

    const int q = tid >> 4;       // query within tile
    const int t = tid & 15;       // sub-thread within query
    const int m = mtile * QPB + q;

    const size_t pbase = ((size_t)b * N2_ + m) * 3;
    const float x2 = p2[pbase + 0];
    const float y2 = p2[pbase + 1];
    const float z2 = p2[pbase + 2];
    const float s2 = __fadd_rn(__fadd_rn(__fmul_rn(x2, x2), __fmul_rn(y2, y2)),
                               __fmul_rn(z2, z2));

    float d0 = FLT_MAX, d1 = FLT_MAX, d2 = FLT_MAX;
    int   i0 = INT_MAX, i1 = INT_MAX, i2 = INT_MAX;

#pragma unroll 4
    for (int n = t; n < N1_; n += TPQ) {
        float4 p = pts[n];
        // dot2 == 2*dot bit-exactly (x2 scaling commutes with RN rounding)
        float dot2 = __fadd_rn(__fadd_rn(__fmul_rn(x2, p.x), __fmul_rn(y2, p.y)),
                               __fmul_rn(z2, p.z));
        float dd = __fadd_rn(__fsub_rn(s2, dot2), p.w);

        // branchless sorted insert (strict less; ascending n => index tiebreak)
        bool c0 = dd < d0;
        bool c1 = dd < d1;
        bool c2 = dd < d2;
        float n0 = fminf(dd, d0);
        float n1 = __builtin_amdgcn_fmed3f(dd, d0, d1);  // d0<=d1 sorted
        float n2 = __builtin_amdgcn_fmed3f(dd, d1, d2);
        int j0 = c0 ? n : i0;
        int j1 = c1 ? (c0 ? i0 : n) : i1;
        int j2 = c2 ? (c1 ? i1 : n) : i2;
        d0 = n0; d1 = n1; d2 = n2;
        i0 = j0; i1 = j1; i2 = j2;
    }

    // Butterfly-merge the 16 partial lists (exact (d,i) lexicographic).
    for (int mask = 1; mask < TPQ; mask <<= 1) {
        float pd0 = __shfl_xor(d0, mask, TPQ);
        float pd1 = __shfl_xor(d1, mask, TPQ);
        float pd2 = __shfl_xor(d2, mask, TPQ);
        int   pi0 = __shfl_xor(i0, mask, TPQ);
        int   pi1 = __shfl_xor(i1, mask, TPQ);
        int   pi2 = __shfl_xor(i2, mask, TPQ);
        ins_(pd0, pi0, d0, d1, d2, i0, i1, i2);
        ins_(pd1, pi1, d0, d1, d2, i0, i1, i2);
        ins_(pd2, pi2, d0, d1, d2, i0, i1, i2);
    }

    if (t == 0) {
        float r0 = 1.0f / __fadd_rn(d0, 1e-8f);
        float r1 = 1.0f / __fadd_rn(d1, 1e-8f);
        float r2 = 1.0f / __fadd_rn(d2, 1e-8f);
        float s  = __fadd_rn(__fadd_rn(r0, r1), r2);
        const size_t o = (size_t)b * N2_ + m;
        wsi[o] = make_int4(i0, i1, i2, 0);
        wsw[o] = make_float4(r0 / s, r1 / s, r2 / s, 0.0f);
    }
}

// ---------------------------------------------------------------------------
// Kernel 2: gather + blend. 4-channel slice (16 KB LDS), half of N2 per
// block -> 1024 blocks (4 blocks/CU). Nontemporal coalesced output stores.
// ---------------------------------------------------------------------------

__global__ __launch_bounds__(256) void blend_kernel(
    const float* __restrict__ x1, const int4* __restrict__ wsi,
    const float4* __restrict__ wsw, float* __restrict__ out) {
    __shared__ float L[4][N1_];   // 16 KB

    int bid = blockIdx.x;
    const int mhalf = bid & 1;
    const int ct    = (bid >> 1) & 63;   // 64 channel tiles of 4
    const int b     = bid >> 7;
    const int tid   = threadIdx.x;

    const float* src = x1 + ((size_t)b * C_ + ct * 4) * N1_;
    float4* Lv = reinterpret_cast<float4*>(&L[0][0]);
    const float4* Sv = reinterpret_cast<const float4*>(src);
#pragma unroll
    for (int j = 0; j < 4; ++j) Lv[tid + 256 * j] = Sv[tid + 256 * j];
    __syncthreads();

    const size_t wbase = (size_t)b * N2_;
    const size_t obase = ((size_t)b * C_ + (size_t)ct * 4) * N2_;

#pragma unroll
    for (int mb = 0; mb < 8; ++mb) {
        const int m = mhalf * 2048 + mb * 256 + tid;
        const int4   id = wsi[wbase + m];
        const float4 w  = wsw[wbase + m];
#pragma unroll
        for (int r = 0; r < 4; ++r) {
            float a  = L[r][id.x];
            float bb = L[r][id.y];
            float cc = L[r][id.z];
            float acc = __fadd_rn(__fadd_rn(__fmul_rn(a,  w.x),
                                            __fmul_rn(bb, w.y)),
                                  __fmul_rn(cc, w.z));
            __builtin_nontemporal_store(acc, &out[obase + (size_t)r * N2_ + m]);
        }
    }
}

extern "C" void kernel_launch(void* const* d_in, const int* in_sizes, int n_in,
                              void* d_out, int out_size, void* d_ws, size_t ws_size,
                              hipStream_t stream) {
    const float* p1 = (const float*)d_in[0];   // [B, N1, 3]
    const float* x1 = (const float*)d_in[1];   // [B, C, N1]
    const float* p2 = (const float*)d_in[2];   // [B, N2, 3]
    float* out = (float*)d_out;                // [B, C, N2]

    int4*   wsi = (int4*)d_ws;
    float4* wsw = (float4*)((char*)d_ws + (size_t)B_ * N2_ * sizeof(int4));

    knn_kernel<<<B_ * (N2_ / QPB), 256, 0, stream>>>(p1, p2, wsi, wsw);
    blend_kernel<<<B_ * (C_ / 4) * 2, 256, 0, stream>>>(x1, wsi, wsw, out);
}